// Round 1
// 308.811 us; speedup vs baseline: 1.0195x; 1.0195x over previous
//
#include <hip/hip_runtime.h>

// Problem: B=32, S=8192, D=256, K=64
//   idx = top_k(attention[b,:], 64) (descending, ties -> lower index first)
//   out[b,k,:] = context[b, idx[b,k], :]
//
// Round 4: split select / gather into two kernels.
//  - select (32 blocks, one per batch): radix-threshold + bitonic, writes idx
//    to workspace. One block per batch is forced by the LDS histogram.
//  - gather (512 blocks): one float4 per thread, whole chip active instead of
//    confining the only HBM-traffic phase to 32 CUs.

constexpr int BATCH   = 32;
constexpr int S       = 8192;
constexpr int D       = 256;
constexpr int K       = 64;
constexpr int THREADS = 256;
constexpr int NBINS   = 16384;   // top 14 bits of mono key
constexpr int CAP     = 256;     // candidate capacity (expected C ~ 75)

__device__ __forceinline__ unsigned int mono_key(float f) {
    unsigned int u = __float_as_uint(f);
    return (u & 0x80000000u) ? ~u : (u | 0x80000000u);  // order-preserving; no NaNs in input
}
__device__ __forceinline__ unsigned long long umax64(unsigned long long a, unsigned long long b) {
    return a > b ? a : b;
}
__device__ __forceinline__ unsigned long long umin64(unsigned long long a, unsigned long long b) {
    return a < b ? a : b;
}

__global__ __launch_bounds__(THREADS) void topk_select_kernel(
    const float* __restrict__ att,   // [B, S]
    int* __restrict__ idx_out)       // [B, K]
{
    const int b    = blockIdx.x;
    const int tid  = threadIdx.x;
    const int lane = tid & 63;
    const int wid  = tid >> 6;

    __shared__ unsigned int       hist[NBINS];              // 64 KB
    __shared__ unsigned long long s_cand[CAP];              // 2 KB
    __shared__ unsigned long long s_sort[THREADS];          // 2 KB
    __shared__ unsigned int       s_wsum[THREADS / 64];
    __shared__ unsigned int       s_cnt, s_chunk, s_above, s_T;

    // ---- zero histogram ----
    for (int i = tid; i < NBINS; i += THREADS) hist[i] = 0u;
    if (tid == 0) s_cnt = 0u;
    __syncthreads();

    // ---- load attention row (coalesced float4), cache in VGPRs, histogram ----
    const float4* arow4 = (const float4*)(att + (size_t)b * S);
    float4 f[8];
#pragma unroll
    for (int j = 0; j < 8; ++j) {
        f[j] = arow4[tid + j * THREADS];
        atomicAdd(&hist[mono_key(f[j].x) >> 18], 1u);
        atomicAdd(&hist[mono_key(f[j].y) >> 18], 1u);
        atomicAdd(&hist[mono_key(f[j].z) >> 18], 1u);
        atomicAdd(&hist[mono_key(f[j].w) >> 18], 1u);
    }
    __syncthreads();

    // ---- per-thread chunk sums (64 bins each; rotated uint4 reads vs bank conflicts) ----
    unsigned int mypart = 0;
    {
        const uint4* h4 = (const uint4*)hist;
        int cb = tid * 16;                       // 16 uint4 = 64 bins
#pragma unroll
        for (int j = 0; j < 16; ++j) {
            uint4 u = h4[cb + ((j + tid) & 15)];
            mypart += u.x + u.y + u.z + u.w;
        }
    }

    // ---- inclusive suffix scan over tid (wave shfl_down scan + cross-wave fix) ----
    unsigned int suf = mypart;
#pragma unroll
    for (int off = 1; off < 64; off <<= 1) {
        unsigned int o = __shfl_down(suf, off, 64);
        if (lane + off < 64) suf += o;
    }
    if (lane == 0) s_wsum[wid] = suf;            // wave total
    __syncthreads();
    for (int w = wid + 1; w < THREADS / 64; ++w) suf += s_wsum[w];
    unsigned int sufnext = suf - mypart;         // count strictly above my chunk

    // exactly one owner chunk: suf >= K crosses to sufnext < K
    if (suf >= (unsigned)K && sufnext < (unsigned)K) {
        s_chunk = (unsigned)tid;
        s_above = sufnext;
    }
    __syncthreads();

    // ---- refine threshold bin within owner chunk (wave 0, ballot) ----
    if (wid == 0) {
        int base = (int)s_chunk * 64;
        unsigned int above = s_above;
        unsigned int cf = hist[base + lane];
#pragma unroll
        for (int off = 1; off < 64; off <<= 1) {
            unsigned int o = __shfl_down(cf, off, 64);
            if (lane + off < 64) cf += o;
        }
        // cf = count of keys in bins [base+lane .. base+63]
        unsigned long long mask = __ballot(above + cf >= (unsigned)K);
        if (lane == 0) s_T = (unsigned)(base + 63 - __clzll(mask));  // max bin with suf >= K
    }
    __syncthreads();
    const unsigned int T = s_T;

    // ---- collect candidates: bin >= T ----
#pragma unroll
    for (int j = 0; j < 8; ++j) {
        int base = 4 * (tid + j * THREADS);
        float v[4] = {f[j].x, f[j].y, f[j].z, f[j].w};
#pragma unroll
        for (int c = 0; c < 4; ++c) {
            unsigned int k32 = mono_key(v[c]);
            if ((k32 >> 18) >= T) {
                unsigned p = atomicAdd(&s_cnt, 1u);
                if (p < (unsigned)CAP)
                    s_cand[p] = ((unsigned long long)k32 << 32) |
                                (unsigned int)(S - 1 - (base + c));
            }
        }
    }
    __syncthreads();

    // ---- 256-wide bitonic sort, descending (pad with 0 < any real key) ----
    unsigned int C = s_cnt;
    unsigned long long key = (tid < (int)C) ? s_cand[tid] : 0ull;

#pragma unroll
    for (int k = 2; k <= THREADS; k <<= 1) {
        for (int j = k >> 1; j > 0; j >>= 1) {
            unsigned long long other;
            if (j < 64) {
                other = __shfl_xor(key, j, 64);
            } else {
                __syncthreads();
                s_sort[tid] = key;
                __syncthreads();
                other = s_sort[tid ^ j];
            }
            bool low     = (tid & j) == 0;
            bool descSeg = (tid & k) == 0;
            key = (low == descSeg) ? umax64(key, other) : umin64(key, other);
        }
    }

    if (tid < K)
        idx_out[b * K + tid] = S - 1 - (int)(unsigned int)(key & 0xFFFFFFFFull);
}

// ---- gather: out[b,k,:] = ctx[b, idx[b,k], :], one float4 per thread ----
constexpr int ROW4     = D / 4;                       // 64 float4 per row
constexpr int GTHREADS = 256;
constexpr int GBLOCKS  = BATCH * K * ROW4 / GTHREADS; // 512 blocks, 2/CU

__global__ __launch_bounds__(GTHREADS) void gather_kernel(
    const float* __restrict__ ctx,   // [B, S, D]
    const int*   __restrict__ idx,   // [B, K]
    float*       __restrict__ out)   // [B, K, D]
{
    const int e  = blockIdx.x * GTHREADS + threadIdx.x;  // [0, B*K*ROW4)
    const int bk = e >> 6;                               // b*K + k   (ROW4 == 64)
    const int c  = e & (ROW4 - 1);
    const int b  = bk >> 6;                              // K == 64
    const int row = idx[bk];                             // broadcast across 64 lanes

    const float4* ctx4 = (const float4*)ctx;
    ((float4*)out)[e] = ctx4[((size_t)b * S + row) * ROW4 + c];
}

extern "C" void kernel_launch(void* const* d_in, const int* in_sizes, int n_in,
                              void* d_out, int out_size, void* d_ws, size_t ws_size,
                              hipStream_t stream) {
    const float* att = (const float*)d_in[0];   // [32, 8192] f32
    const float* ctx = (const float*)d_in[1];   // [32, 8192, 256] f32
    // d_in[2] is K (scalar int) == 64, compile-time constant here.
    float* out = (float*)d_out;                 // [32, 64, 256] f32
    int*   idx = (int*)d_ws;                    // 32*64 ints = 8 KB of workspace

    topk_select_kernel<<<BATCH, THREADS, 0, stream>>>(att, idx);
    gather_kernel<<<GBLOCKS, GTHREADS, 0, stream>>>(ctx, idx, out);
}